// Round 8
// baseline (588.844 us; speedup 1.0000x reference)
//
#include <hip/hip_runtime.h>
#include <hip/hip_bf16.h>
#include <cstdint>

typedef unsigned short u16;
typedef unsigned int   u32;
typedef __attribute__((ext_vector_type(8))) short bf16x8;  // 8 bf16 = 4 VGPRs
typedef __attribute__((ext_vector_type(4))) float f32x4;

#define NEG_LOG2E -1.44269504088896f

__device__ __forceinline__ float bf2f(u16 u) {
    union { u32 i; float f; } c; c.i = ((u32)u) << 16; return c.f;
}
__device__ __forceinline__ u16 f2bf(float f) {
    union { float f; u32 i; } c; c.f = f;
    u32 x = c.i;
    return (u16)((x + 0x7fffu + ((x >> 16) & 1u)) >> 16);  // RNE
}
// unpack packed bf16 pair (2 VALU: lshl + and)
__device__ __forceinline__ void bfu2(u32 p, float& lo, float& hi) {
    union { u32 i; float f; } a, b;
    a.i = p << 16; b.i = p & 0xffff0000u;
    lo = a.f; hi = b.f;
}
// gate = sigmoid(k+q) given zt = -log2e*(k+q):  rcp(1 + exp2(zt))
__device__ __forceinline__ float gate(float zt) {
    return __builtin_amdgcn_rcpf(1.0f + __builtin_amdgcn_exp2f(zt));
}

#define CSR_CH 2048
#define XS 136  // 128 + 8 pad -> 2-way LDS bank aliasing (free per m136)

// ---------------------------------------------------------------------------
// Launch 1: prep (weight transpose+cast, 64 blocks) + direct-atomic histogram
// (NA blocks). Round-7 head restructure: the 4-pass sort (hist/scan/sortA/
// sortB) was ~80 us of mostly-unoverlapped dispatches; with avg degree 16 the
// contention is low enough for a 2-pass atomic CSR build.
struct P8 { const float* p[8]; };
__global__ __launch_bounds__(256)
void prep_hist2_k(P8 wsrc, u16* __restrict__ Wt,
                  const int* __restrict__ dst, int* __restrict__ cnt, int nE) {
    int t = threadIdx.x;
    if (blockIdx.x < 64) {
        int mat = blockIdx.x >> 3, seg = blockIdx.x & 7;
        const float* W = wsrc.p[mat];
        u16* T = Wt + (size_t)mat * 16384;
        for (int p = 0; p < 8; ++p) {
            int idx = seg * 2048 + p * 256 + t;
            int k = idx >> 7, n = idx & 127;
            T[n * 128 + k] = f2bf(W[k * 128 + n]);
        }
    } else {
        int b = blockIdx.x - 64;
        int i0 = b * CSR_CH, iend = min(i0 + CSR_CH, nE);
        for (int i = i0 + t; i < iend; i += 256)
            atomicAdd(&cnt[dst[i]], 1);
    }
}

// ---------------------------------------------------------------------------
// scan phase 1: per-block (1024-elem chunk) total
__global__ __launch_bounds__(256)
void scan_part_k(const int* __restrict__ arr, int* __restrict__ part, int M) {
    __shared__ int wsum[4];
    int t = threadIdx.x, lane = t & 63, wave = t >> 6;
    int i0 = blockIdx.x * 1024 + t * 4;
    int s = 0;
    for (int j = 0; j < 4; ++j) { int i = i0 + j; if (i < M) s += arr[i]; }
    for (int off = 32; off > 0; off >>= 1) s += __shfl_xor(s, off);
    if (lane == 0) wsum[wave] = s;
    __syncthreads();
    if (t == 0) part[blockIdx.x] = wsum[0] + wsum[1] + wsum[2] + wsum[3];
}

// scan phase 2+3 merged: every block scans the (<=512) partials in LDS,
// takes its own exclusive base, then emits its chunk. Writes rowp AND a
// working copy (cur) used by the atomic scatter.
__global__ __launch_bounds__(256)
void scan_emit2_k(const int* __restrict__ arr, const int* __restrict__ part,
                  int* __restrict__ outp, int* __restrict__ cur,
                  int M, int total, int nparts) {
    __shared__ int sh[512];
    __shared__ int woff[4];
    int t = threadIdx.x, lane = t & 63, wave = t >> 6;
    sh[t]       = (t < nparts)       ? part[t]       : 0;
    sh[t + 256] = (t + 256 < nparts) ? part[t + 256] : 0;
    __syncthreads();
    for (int off = 1; off < 512; off <<= 1) {
        int u0 = (t >= off)       ? sh[t - off]       : 0;
        int u1 = (t + 256 >= off) ? sh[t + 256 - off] : 0;
        __syncthreads();
        sh[t] += u0; sh[t + 256] += u1;
        __syncthreads();
    }
    int base = (blockIdx.x == 0) ? 0 : sh[blockIdx.x - 1];
    __syncthreads();

    int i0 = blockIdx.x * 1024 + t * 4;
    int d[4]; int s = 0;
    for (int j = 0; j < 4; ++j) { int i = i0 + j; d[j] = (i < M) ? arr[i] : 0; s += d[j]; }
    int ws = s;
    for (int off = 1; off < 64; off <<= 1) {
        int u = __shfl_up(ws, off);
        if (lane >= off) ws += u;
    }
    if (lane == 63) woff[wave] = ws;
    __syncthreads();
    for (int w = 0; w < wave; ++w) base += woff[w];
    int ex = base + ws - s;
    for (int j = 0; j < 4; ++j) {
        int i = i0 + j;
        if (i < M) { outp[i] = ex; cur[i] = ex; }
        ex += d[j];
    }
    if (blockIdx.x == 0 && t == 0) outp[M] = total;  // sentinel
}

// ---------------------------------------------------------------------------
// GEMM body (operand-swapped). LDS holds ONLY the X tile (34 KB). Weight
// A-fragments come straight from global (weights 256 KB total, L2-hot).
// nt-MAJOR dual-matrix schedule (round-6 spill post-mortem: arg2 of
// launch_bounds caps VGPR at 256/arg2 on this hipcc — 64 at arg2=4 — and
// the wi-sequential body needed ~130 live regs -> scratch storm). Both
// matrices of a store-pair run per output tile: per nt, 4 independent MFMA
// chains over kt, then one immediate dwordx4 store per mt. Live ~105 VGPR,
// bound (256,2) = proven-no-spill 128 cap.
// KS: per node 256 u16, k4/s4 interleaved. QV: q4/v4. Per wave, mt0+mt1
// stores cover a full 128B line per node (dense writes).
template<int F32>
__device__ __forceinline__
void gemm_body(int bid, u16* xs,
               const void* __restrict__ Xv, const u16* __restrict__ Wt,
               const float* __restrict__ bias,
               u16* __restrict__ KS, u16* __restrict__ QV, int nrows)
{
    const int tid  = threadIdx.x;
    const int wave = tid >> 6, lane = tid & 63;
    const int quad = lane >> 4, l16 = lane & 15;
    const int r0 = bid * 128;

    for (int p = 0; p < 8; ++p) {
        int c = p * 256 + tid;
        int row = c >> 4;
        int col = (c & 15) * 8;
        int gr = r0 + row; if (gr >= nrows) gr = nrows - 1;
        if (F32) {
            const float* sp = (const float*)Xv + (size_t)gr * 128 + col;
            float4 f0 = *(const float4*)(sp);
            float4 f1 = *(const float4*)(sp + 4);
            uint4 st;
            st.x = ((u32)f2bf(f0.y) << 16) | f2bf(f0.x);
            st.y = ((u32)f2bf(f0.w) << 16) | f2bf(f0.z);
            st.z = ((u32)f2bf(f1.y) << 16) | f2bf(f1.x);
            st.w = ((u32)f2bf(f1.w) << 16) | f2bf(f1.z);
            *(uint4*)(&xs[row * XS + col]) = st;
        } else {
            uint4 d = *(const uint4*)((const u16*)Xv + (size_t)gr * 128 + col);
            *(uint4*)(&xs[row * XS + col]) = d;
        }
    }
    __syncthreads();   // xs is read-only from here on: single barrier

    const int cbase = wave * 32;  // this wave's 32 output channels

    for (int pass = 0; pass < 2; ++pass) {
        const u16* WA = Wt + (size_t)(pass ? 0 : 1) * 16384;  // K : Q
        const u16* WB = Wt + (size_t)(pass ? 3 : 2) * 16384;  // S : V

        // both matrices' A-fragments straight from global (L2-hot): 64 VGPR
        bf16x8 afA0[4], afA1[4], afB0[4], afB1[4];
        for (int kt = 0; kt < 4; ++kt) {
            const int ro0 = (cbase + l16)      * 128 + kt * 32 + quad * 8;
            const int ro1 = (cbase + 16 + l16) * 128 + kt * 32 + quad * 8;
            afA0[kt] = *(const bf16x8*)(WA + ro0);
            afA1[kt] = *(const bf16x8*)(WA + ro1);
            afB0[kt] = *(const bf16x8*)(WB + ro0);
            afB1[kt] = *(const bf16x8*)(WB + ro1);
        }

        float4 bias4[2];
        if (pass) {
            bias4[0] = *(const float4*)(bias + cbase + quad * 4);
            bias4[1] = *(const float4*)(bias + cbase + 16 + quad * 4);
        }

        for (int nt = 0; nt < 8; ++nt) {
            f32x4 aA0 = (f32x4)0.0f, aA1 = (f32x4)0.0f;
            f32x4 aB0 = (f32x4)0.0f, aB1 = (f32x4)0.0f;
            for (int kt = 0; kt < 4; ++kt) {
                bf16x8 b = *(const bf16x8*)&xs[(nt * 16 + l16) * XS + kt * 32 + quad * 8];
                aA0 = __builtin_amdgcn_mfma_f32_16x16x32_bf16(afA0[kt], b, aA0, 0, 0, 0);
                aA1 = __builtin_amdgcn_mfma_f32_16x16x32_bf16(afA1[kt], b, aA1, 0, 0, 0);
                aB0 = __builtin_amdgcn_mfma_f32_16x16x32_bf16(afB0[kt], b, aB0, 0, 0, 0);
                aB1 = __builtin_amdgcn_mfma_f32_16x16x32_bf16(afB1[kt], b, aB1, 0, 0, 0);
            }
            int node = r0 + nt * 16 + l16;
            if (node >= nrows) continue;
            u16* rowbase = (pass ? KS : QV) + (size_t)node * 256;
            // mt = 0
            {
                float x0 = aA0[0] * NEG_LOG2E, x1 = aA0[1] * NEG_LOG2E;
                float x2 = aA0[2] * NEG_LOG2E, x3 = aA0[3] * NEG_LOG2E;
                float y0 = aB0[0], y1 = aB0[1], y2 = aB0[2], y3 = aB0[3];
                if (pass) { y0 += bias4[0].x; y1 += bias4[0].y; y2 += bias4[0].z; y3 += bias4[0].w; }
                uint4 out;
                out.x = ((u32)f2bf(x1) << 16) | f2bf(x0);
                out.y = ((u32)f2bf(x3) << 16) | f2bf(x2);
                out.z = ((u32)f2bf(y1) << 16) | f2bf(y0);
                out.w = ((u32)f2bf(y3) << 16) | f2bf(y2);
                *(uint4*)(rowbase + 2 * (cbase + quad * 4)) = out;
            }
            // mt = 1
            {
                float x0 = aA1[0] * NEG_LOG2E, x1 = aA1[1] * NEG_LOG2E;
                float x2 = aA1[2] * NEG_LOG2E, x3 = aA1[3] * NEG_LOG2E;
                float y0 = aB1[0], y1 = aB1[1], y2 = aB1[2], y3 = aB1[3];
                if (pass) { y0 += bias4[1].x; y1 += bias4[1].y; y2 += bias4[1].z; y3 += bias4[1].w; }
                uint4 out;
                out.x = ((u32)f2bf(x1) << 16) | f2bf(x0);
                out.y = ((u32)f2bf(x3) << 16) | f2bf(x2);
                out.z = ((u32)f2bf(y1) << 16) | f2bf(y0);
                out.w = ((u32)f2bf(y3) << 16) | f2bf(y2);
                *(uint4*)(rowbase + 2 * (cbase + 16 + quad * 4)) = out;
            }
        }
    }
}

// Launch 3: layer-1 GEMM (first gb blocks — the long pole, starts first) +
// atomic CSR scatter (remaining NA blocks): ssrc[atomicAdd(&cur[dst],1)]=src.
// Within-row edge order becomes nondeterministic — harmless (order only
// perturbs float-sum rounding; threshold has 1.8x slack).
__global__ __launch_bounds__(256, 2)
void scat_gemm1(const int* __restrict__ src, const int* __restrict__ dst,
                int* __restrict__ cur, int* __restrict__ ssrc,
                int nE, int gb,
                const float* __restrict__ x0, const u16* __restrict__ Wt,
                const float* __restrict__ bias,
                u16* __restrict__ KS, u16* __restrict__ QV, int N)
{
    __shared__ u16 xs[128 * XS];
    if ((int)blockIdx.x < gb) {
        gemm_body<1>(blockIdx.x, xs, x0, Wt, bias, KS, QV, N);
    } else {
        int b = blockIdx.x - gb;
        int i0 = b * CSR_CH, iend = min(i0 + CSR_CH, nE);
        for (int i = i0 + threadIdx.x; i < iend; i += 256) {
            int d = dst[i], s = src[i];
            int r = atomicAdd(&cur[d], 1);
            ssrc[r] = s;
        }
    }
}

// Layer-2 standalone GEMM
__global__ __launch_bounds__(256, 2)
void gemm_l2(const u16* __restrict__ X, const u16* __restrict__ Wt,
             const float* __restrict__ bias,
             u16* __restrict__ KS, u16* __restrict__ QV, int nrows)
{
    __shared__ u16 xs[128 * XS];
    gemm_body<0>(blockIdx.x, xs, X, Wt, bias, KS, QV, nrows);
}

// ---------------------------------------------------------------------------
// CSR gather-reduce edge phase: one wave per dst node, TWO edges per load
// (half-wave per edge, lane covers 4 channels via one dwordx4 row load).
// Row-level software pipeline: next row's ssrc block, merged KS row, and row
// pointers are in flight during current row's compute; next row's first
// gather group issued over the epilogue. KS is k4/s4-interleaved so one
// dwordx4 fetches K+S for a 4-channel group.
template<int MODE>
__global__ __launch_bounds__(256)
void edge_csr2(const int* __restrict__ rowp, const int* __restrict__ ssrc,
               const u16* __restrict__ KS, const u16* __restrict__ QV,
               u16* __restrict__ Xout,
               const float* __restrict__ Wk3, const float* __restrict__ Wq3,
               const float* __restrict__ Wv3, const float* __restrict__ Ws3,
               const float* __restrict__ b3,
               float* __restrict__ k3, float2* __restrict__ qv3,
               float* __restrict__ s3, int N)
{
    const int lane = threadIdx.x & 63;
    const int half = lane >> 5;
    const int t    = lane & 31;       // channel group: channels 4t..4t+3
    int gw = blockIdx.x * (blockDim.x >> 6) + (threadIdx.x >> 6);
    int nw = gridDim.x * (blockDim.x >> 6);

    float4 wk4, wq4, wv4, ws4;
    float bias3 = 0.0f;
    if (MODE == 1) {
        wk4 = *(const float4*)(Wk3 + 4 * t);
        wq4 = *(const float4*)(Wq3 + 4 * t);
        wv4 = *(const float4*)(Wv3 + 4 * t);
        ws4 = *(const float4*)(Ws3 + 4 * t);
        bias3 = b3[0];
    }

#define LOAD2(S0, S1) (*((const uint4*)(QV + (size_t)(half ? (S1) : (S0)) * 256) + t))
#define COMP(QVv, A0, A1, A2, A3)                                             \
    {                                                                         \
        float q0_, q1_, q2_, q3_, v0_, v1_, v2_, v3_;                         \
        bfu2((QVv).x, q0_, q1_); bfu2((QVv).y, q2_, q3_);                     \
        bfu2((QVv).z, v0_, v1_); bfu2((QVv).w, v2_, v3_);                     \
        A0 += gate(k0 + q0_) * v0_;  A1 += gate(k1 + q1_) * v1_;              \
        A2 += gate(k2 + q2_) * v2_;  A3 += gate(k3v + q3_) * v3_;             \
    }
// load one 4-edge group g: two dwordx4 gathers (edges 4g..4g+3)
#define LOADG(SVV, G, RA, RB)                                                 \
    {                                                                         \
        int s0_ = __builtin_amdgcn_readlane(SVV, 4 * (G));                    \
        int s1_ = __builtin_amdgcn_readlane(SVV, 4 * (G) + 1);                \
        int s2_ = __builtin_amdgcn_readlane(SVV, 4 * (G) + 2);                \
        int s3_ = __builtin_amdgcn_readlane(SVV, 4 * (G) + 3);                \
        RA = LOAD2(s0_, s1_); RB = LOAD2(s2_, s3_);                           \
    }

    int d = gw;
    int beg = 0, end = 0, sv = 0;
    uint4 ks; ks.x = ks.y = ks.z = ks.w = 0u;
    if (d < N) {
        beg = rowp[d]; end = rowp[d + 1];
        int e  = beg + lane;
        int ec = (end > beg) ? ((e < end) ? e : end - 1) : 0;
        sv = ssrc[ec];
        ks = *((const uint4*)KS + (size_t)d * 32 + t);
    }
    int havePF = 0;
    uint4 pA, pB;
    pA.x = pA.y = pA.z = pA.w = 0u;
    pB = pA;

    while (d < N) {
        int dn = d + nw;
        int begN = 0, endN = 0, svN = 0;
        uint4 ksN; ksN.x = ksN.y = ksN.z = ksN.w = 0u;
        if (dn < N) {
            begN = rowp[dn]; endN = rowp[dn + 1];
            int e  = begN + lane;
            int ec = (endN > begN) ? ((e < endN) ? e : endN - 1) : 0;
            svN = ssrc[ec];
            ksN = *((const uint4*)KS + (size_t)dn * 32 + t);
        }

        float k0, k1, k2, k3v;
        bfu2(ks.x, k0, k1); bfu2(ks.y, k2, k3v);
        float a0 = 0.f, a1 = 0.f, a2 = 0.f, a3 = 0.f;
        float e0 = 0.f, e1 = 0.f, e2 = 0.f, e3 = 0.f;

        for (int base = beg; base < end; base += 64) {
            if (base > beg) {            // rare multi-block row: reload sv
                int e  = base + lane;
                int ec = (e < end) ? e : end - 1;
                sv = ssrc[ec];
            }
            int m = end - base; if (m > 64) m = 64;
            int ng = m >> 2;
            int j = ng << 2;
            if (ng > 0) {
                uint4 xA, xB, yA, yB;
                if (havePF && base == beg) { xA = pA; xB = pB; }
                else LOADG(sv, 0, xA, xB);
                int g = 1;
                for (; g + 1 < ng; g += 2) {          // ping-pong groups
                    LOADG(sv, g, yA, yB);
                    COMP(xA, a0, a1, a2, a3);
                    COMP(xB, e0, e1, e2, e3);
                    LOADG(sv, g + 1, xA, xB);
                    COMP(yA, a0, a1, a2, a3);
                    COMP(yB, e0, e1, e2, e3);
                }
                if (g < ng) {
                    LOADG(sv, g, yA, yB);
                    COMP(xA, a0, a1, a2, a3);
                    COMP(xB, e0, e1, e2, e3);
                    COMP(yA, a0, a1, a2, a3);
                    COMP(yB, e0, e1, e2, e3);
                } else {
                    COMP(xA, a0, a1, a2, a3);
                    COMP(xB, e0, e1, e2, e3);
                }
            }
            if (j + 2 <= m) {
                int s0 = __builtin_amdgcn_readlane(sv, j);
                int s1 = __builtin_amdgcn_readlane(sv, j + 1);
                uint4 qA = LOAD2(s0, s1);
                COMP(qA, a0, a1, a2, a3);
                j += 2;
            }
            if (j < m) {  // single odd edge: only half 0 accumulates
                int s0i = __builtin_amdgcn_readlane(sv, j);
                uint4 qv_ = *((const uint4*)(QV + (size_t)s0i * 256) + t);
                float q0_, q1_, q2_, q3_, v0_, v1_, v2_, v3_;
                bfu2(qv_.x, q0_, q1_); bfu2(qv_.y, q2_, q3_);
                bfu2(qv_.z, v0_, v1_); bfu2(qv_.w, v2_, v3_);
                if (half == 0) {
                    a0 += gate(k0 + q0_) * v0_;  a1 += gate(k1 + q1_) * v1_;
                    a2 += gate(k2 + q2_) * v2_;  a3 += gate(k3v + q3_) * v3_;
                }
            }
        }

        // early-issue next row's first gather group (svN has arrived by now);
        // it flies over the epilogue + next-row prologue.
        havePF = 0;
        if (dn < N) {
            int mN = endN - begN; if (mN > 64) mN = 64;
            if ((mN >> 2) > 0) {
                int s0_ = __builtin_amdgcn_readlane(svN, 0);
                int s1_ = __builtin_amdgcn_readlane(svN, 1);
                int s2_ = __builtin_amdgcn_readlane(svN, 2);
                int s3_ = __builtin_amdgcn_readlane(svN, 3);
                pA = LOAD2(s0_, s1_);
                pB = LOAD2(s2_, s3_);
                havePF = 1;
            }
        }
#undef LOADG
#undef LOAD2
#undef COMP

        a0 += e0; a1 += e1; a2 += e2; a3 += e3;
        a0 += __shfl_xor(a0, 32);
        a1 += __shfl_xor(a1, 32);
        a2 += __shfl_xor(a2, 32);
        a3 += __shfl_xor(a3, 32);

        float s0f, s1f, s2f, s3f;
        bfu2(ks.z, s0f, s1f); bfu2(ks.w, s2f, s3f);
        float r0 = fmaxf(s0f + a0, 0.f);
        float r1 = fmaxf(s1f + a1, 0.f);
        float r2 = fmaxf(s2f + a2, 0.f);
        float r3 = fmaxf(s3f + a3, 0.f);

        if (MODE == 0) {
            if (half == 0) {
                uint2 st;
                st.x = ((u32)f2bf(r1) << 16) | f2bf(r0);
                st.y = ((u32)f2bf(r3) << 16) | f2bf(r2);
                *(uint2*)(Xout + (size_t)d * 128 + t * 4) = st;
            }
        } else {
            float pk = r0 * wk4.x + r1 * wk4.y + r2 * wk4.z + r3 * wk4.w;
            float pq = r0 * wq4.x + r1 * wq4.y + r2 * wq4.z + r3 * wq4.w;
            float pv = r0 * wv4.x + r1 * wv4.y + r2 * wv4.z + r3 * wv4.w;
            float ps = r0 * ws4.x + r1 * ws4.y + r2 * ws4.z + r3 * ws4.w;
            for (int off = 1; off < 32; off <<= 1) {
                pk += __shfl_xor(pk, off);
                pq += __shfl_xor(pq, off);
                pv += __shfl_xor(pv, off);
                ps += __shfl_xor(ps, off);
            }
            if (lane == 0) {
                k3[d]  = NEG_LOG2E * pk;
                qv3[d] = make_float2(NEG_LOG2E * pq, pv);
                s3[d]  = ps + bias3;
            }
        }

        d = dn; beg = begN; end = endN; sv = svN; ks = ksN;
    }
}

// ---------------------------------------------------------------------------
// CSR edge phase, Dout=1: wave per node; qv3 packed float2 (one 8B gather).
// Same 1-deep row prefetch (rowp/ssrc/k3/s3 for the next row in flight).
__global__ __launch_bounds__(256)
void edge3_csr(const int* __restrict__ rowp, const int* __restrict__ ssrc,
               const float* __restrict__ k3, const float2* __restrict__ qv3,
               const float* __restrict__ s3, float* __restrict__ outp, int N)
{
    int lane = threadIdx.x & 63;
    int gw = blockIdx.x * (blockDim.x >> 6) + (threadIdx.x >> 6);
    int nw = gridDim.x * (blockDim.x >> 6);

    int d = gw;
    int beg = 0, end = 0, sv = 0;
    float kd = 0.f, sd = 0.f;
    if (d < N) {
        beg = rowp[d]; end = rowp[d + 1];
        int e  = beg + lane;
        int ec = (end > beg) ? ((e < end) ? e : end - 1) : 0;
        sv = ssrc[ec];
        kd = k3[d]; sd = s3[d];
    }
    while (d < N) {
        int dn = d + nw;
        int begN = 0, endN = 0, svN = 0;
        float kdN = 0.f, sdN = 0.f;
        if (dn < N) {
            begN = rowp[dn]; endN = rowp[dn + 1];
            int e  = begN + lane;
            int ec = (endN > begN) ? ((e < endN) ? e : endN - 1) : 0;
            svN = ssrc[ec];
            kdN = k3[dn]; sdN = s3[dn];
        }

        float sum = 0.0f;
        int m = end - beg;
        if (lane < m) {                    // first 64 edges via prefetched sv
            float2 qv = qv3[sv];
            sum = gate(kd + qv.x) * qv.y;
        }
        for (int e = beg + 64 + lane; e < end; e += 64) {   // rare deg>64
            float2 qv = qv3[ssrc[e]];
            sum += gate(kd + qv.x) * qv.y;
        }
        for (int off = 32; off > 0; off >>= 1) sum += __shfl_xor(sum, off);
        if (lane == 0) outp[d] = sd + sum;

        d = dn; beg = begN; end = endN; sv = svN; kd = kdN; sd = sdN;
    }
}

// ---------------------------------------------------------------------------
extern "C" void kernel_launch(void* const* d_in, const int* in_sizes, int n_in,
                              void* d_out, int out_size, void* d_ws, size_t ws_size,
                              hipStream_t stream)
{
    const float* x0 = (const float*)d_in[0];
    const int*   ei = (const int*)d_in[1];
    const int    N  = in_sizes[0] / 128;   // 100000
    const int    E  = in_sizes[1] / 2;     // 1600000
    const int* src = ei;
    const int* dst = ei + E;

    const int NA     = (E + CSR_CH - 1) / CSR_CH;   // 782
    const int nparts = (N + 1023) / 1024;           // 98

    char* ws = (char*)d_ws;
    size_t off = 0;
    auto carve = [&](size_t bytes) { void* p = ws + off; off += (bytes + 255) & ~(size_t)255; return p; };
    u16*    Wt   = (u16*)carve((size_t)8 * 16384 * sizeof(u16));
    u16*    bufX = (u16*)carve((size_t)N * 128 * sizeof(u16));
    u16*    KS   = (u16*)carve((size_t)N * 256 * sizeof(u16));
    u16*    QV   = (u16*)carve((size_t)N * 256 * sizeof(u16));
    int*    ssrc = (int*)carve((size_t)E * sizeof(int));
    int*    rowp = (int*)carve((size_t)(N + 1) * sizeof(int));
    int*    cnt  = (int*)carve((size_t)N * sizeof(int));
    int*    cur  = (int*)carve((size_t)N * sizeof(int));
    int*    part = (int*)carve((size_t)512 * sizeof(int));
    float*  k3   = (float*)carve((size_t)N * sizeof(float));
    float2* qv3  = (float2*)carve((size_t)N * sizeof(float2));
    float*  s3   = (float*)carve((size_t)N * sizeof(float));

    P8 wp;
    wp.p[0] = (const float*)d_in[2];  wp.p[1] = (const float*)d_in[3];
    wp.p[2] = (const float*)d_in[4];  wp.p[3] = (const float*)d_in[5];
    wp.p[4] = (const float*)d_in[7];  wp.p[5] = (const float*)d_in[8];
    wp.p[6] = (const float*)d_in[9];  wp.p[7] = (const float*)d_in[10];

    int gb = (N + 127) / 128;   // 782

    // 0: zero the histogram (graph-capture-safe async memset)
    hipMemsetAsync(cnt, 0, (size_t)N * sizeof(int), stream);
    // 1: weight prep + direct-atomic histogram (one launch)
    prep_hist2_k<<<64 + NA, 256, 0, stream>>>(wp, Wt, dst, cnt, E);
    // 2: scan over N (writes rowp + working copy cur)
    scan_part_k<<<nparts, 256, 0, stream>>>(cnt, part, N);
    scan_emit2_k<<<nparts, 256, 0, stream>>>(cnt, part, rowp, cur, N, E, nparts);
    // 3: layer-1 GEMM (long pole, blocks first) + atomic CSR scatter
    scat_gemm1<<<gb + NA, 256, 0, stream>>>(src, dst, cur, ssrc, E, gb,
        x0, Wt, (const float*)d_in[6], KS, QV, N);
    // 4: layer-1 edge
    edge_csr2<0><<<4096, 256, 0, stream>>>(rowp, ssrc, KS, QV, bufX,
        nullptr, nullptr, nullptr, nullptr, nullptr, nullptr, nullptr, nullptr, N);
    // 5: layer-2 GEMM
    gemm_l2<<<gb, 256, 0, stream>>>(bufX, Wt + 4 * 16384, (const float*)d_in[11], KS, QV, N);
    // 6: layer-2 edge (+ fused layer-3 GEMV)
    edge_csr2<1><<<4096, 256, 0, stream>>>(rowp, ssrc, KS, QV, nullptr,
        (const float*)d_in[12], (const float*)d_in[13], (const float*)d_in[14],
        (const float*)d_in[15], (const float*)d_in[16],
        k3, qv3, s3, N);
    // 7: layer-3 edge -> d_out
    edge3_csr<<<2048, 256, 0, stream>>>(rowp, ssrc, k3, qv3, s3, (float*)d_out, N);
}

// Round 9
// 495.159 us; speedup vs baseline: 1.1892x; 1.1892x over previous
//
#include <hip/hip_runtime.h>
#include <hip/hip_bf16.h>
#include <cstdint>

typedef unsigned short u16;
typedef unsigned int   u32;
typedef __attribute__((ext_vector_type(8))) short bf16x8;  // 8 bf16 = 4 VGPRs
typedef __attribute__((ext_vector_type(4))) float f32x4;

#define NEG_LOG2E -1.44269504088896f

__device__ __forceinline__ float bf2f(u16 u) {
    union { u32 i; float f; } c; c.i = ((u32)u) << 16; return c.f;
}
__device__ __forceinline__ u16 f2bf(float f) {
    union { float f; u32 i; } c; c.f = f;
    u32 x = c.i;
    return (u16)((x + 0x7fffu + ((x >> 16) & 1u)) >> 16);  // RNE
}
// unpack packed bf16 pair (2 VALU: lshl + and)
__device__ __forceinline__ void bfu2(u32 p, float& lo, float& hi) {
    union { u32 i; float f; } a, b;
    a.i = p << 16; b.i = p & 0xffff0000u;
    lo = a.f; hi = b.f;
}
// gate = sigmoid(k+q) given zt = -log2e*(k+q):  rcp(1 + exp2(zt))
__device__ __forceinline__ float gate(float zt) {
    return __builtin_amdgcn_rcpf(1.0f + __builtin_amdgcn_exp2f(zt));
}

#define CSR_CH 2048
#define XS 136  // 128 + 8 pad -> 2-way LDS bank aliasing (free per m136)

// ---------------------------------------------------------------------------
// Launch 1: prep (weight transpose+cast, 64 blocks) + sortA_hist (NA blocks)
// (Round-8 post-mortem: direct global-atomic CSR build was +85us — the
// LDS-histogram 4-pass sort is the best measured head; restored here.)
struct P8 { const float* p[8]; };
__global__ __launch_bounds__(256)
void prep_hist_k(P8 wsrc, u16* __restrict__ Wt,
                 const int* __restrict__ dst, int* __restrict__ cnt,
                 int nE, int NA, int nbuck) {
    __shared__ int lh[512];
    int t = threadIdx.x;
    if (blockIdx.x < 64) {
        int mat = blockIdx.x >> 3, seg = blockIdx.x & 7;
        const float* W = wsrc.p[mat];
        u16* T = Wt + (size_t)mat * 16384;
        for (int p = 0; p < 8; ++p) {
            int idx = seg * 2048 + p * 256 + t;
            int k = idx >> 7, n = idx & 127;
            T[n * 128 + k] = f2bf(W[k * 128 + n]);
        }
    } else {
        int b = blockIdx.x - 64;
        for (int i = t; i < nbuck; i += 256) lh[i] = 0;
        __syncthreads();
        int i0 = b * CSR_CH, iend = min(i0 + CSR_CH, nE);
        for (int i = i0 + t; i < iend; i += 256) atomicAdd(&lh[dst[i] >> 8], 1);
        __syncthreads();
        for (int i = t; i < nbuck; i += 256) cnt[i * NA + b] = lh[i];
    }
}

// ---------------------------------------------------------------------------
// scan phase 1: per-block (1024-elem chunk) total
__global__ __launch_bounds__(256)
void scan_part_k(const int* __restrict__ arr, int* __restrict__ part, int M) {
    __shared__ int wsum[4];
    int t = threadIdx.x, lane = t & 63, wave = t >> 6;
    int i0 = blockIdx.x * 1024 + t * 4;
    int s = 0;
    for (int j = 0; j < 4; ++j) { int i = i0 + j; if (i < M) s += arr[i]; }
    for (int off = 32; off > 0; off >>= 1) s += __shfl_xor(s, off);
    if (lane == 0) wsum[wave] = s;
    __syncthreads();
    if (t == 0) part[blockIdx.x] = wsum[0] + wsum[1] + wsum[2] + wsum[3];
}

// scan phase 2+3 merged: every block scans the (<=512) partials in LDS
// (redundant, ~1KB), takes its own exclusive base, then emits its chunk.
__global__ __launch_bounds__(256)
void scan_emit2_k(const int* __restrict__ arr, const int* __restrict__ part,
                  int* __restrict__ outp, int M, int total, int nparts) {
    __shared__ int sh[512];
    __shared__ int woff[4];
    int t = threadIdx.x, lane = t & 63, wave = t >> 6;
    sh[t]       = (t < nparts)       ? part[t]       : 0;
    sh[t + 256] = (t + 256 < nparts) ? part[t + 256] : 0;
    __syncthreads();
    for (int off = 1; off < 512; off <<= 1) {
        int u0 = (t >= off)       ? sh[t - off]       : 0;
        int u1 = (t + 256 >= off) ? sh[t + 256 - off] : 0;
        __syncthreads();
        sh[t] += u0; sh[t + 256] += u1;
        __syncthreads();
    }
    int base = (blockIdx.x == 0) ? 0 : sh[blockIdx.x - 1];
    __syncthreads();

    int i0 = blockIdx.x * 1024 + t * 4;
    int d[4]; int s = 0;
    for (int j = 0; j < 4; ++j) { int i = i0 + j; d[j] = (i < M) ? arr[i] : 0; s += d[j]; }
    int ws = s;
    for (int off = 1; off < 64; off <<= 1) {
        int u = __shfl_up(ws, off);
        if (lane >= off) ws += u;
    }
    if (lane == 63) woff[wave] = ws;
    __syncthreads();
    for (int w = 0; w < wave; ++w) base += woff[w];
    int ex = base + ws - s;
    for (int j = 0; j < 4; ++j) {
        int i = i0 + j;
        if (i < M) outp[i] = ex;
        ex += d[j];
    }
    if (blockIdx.x == 0 && t == 0) outp[M] = total;  // sentinel
}

// ---------------------------------------------------------------------------
// sortB body: per-bucket fine grouping (uses caller-provided LDS)
__device__ __forceinline__
void sortB_body(const u32* __restrict__ tkey, const int* __restrict__ scnt,
                int* __restrict__ rowp, int* __restrict__ ssrc,
                int NA, int N, int nE, int b, int* h, int* offv) {
    int t = threadIdx.x;
    int base = scnt[b * NA];
    int endp = scnt[(b + 1) * NA];   // sentinel covers last bucket
    h[t] = 0;
    __syncthreads();
    for (int i = base + t; i < endp; i += 256)
        atomicAdd(&h[tkey[i] >> 24], 1);
    __syncthreads();
    int v = h[t];
    offv[t] = v;
    __syncthreads();
    for (int d = 1; d < 256; d <<= 1) {
        int u = (t >= d) ? offv[t - d] : 0;
        __syncthreads();
        offv[t] += u;
        __syncthreads();
    }
    int ex = offv[t] - v;
    __syncthreads();
    offv[t] = ex;
    h[t] = 0;
    __syncthreads();
    int dglob = b * 256 + t;
    if (dglob < N) rowp[dglob] = base + ex;
    if (b == 0 && t == 0) rowp[N] = nE;
    for (int i = base + t; i < endp; i += 256) {
        u32 k = tkey[i];
        int loc = k >> 24;
        int r = atomicAdd(&h[loc], 1);
        ssrc[base + offv[loc] + r] = (int)(k & 0xFFFFFFu);
    }
}

// sortB standalone (round-9 head reorder: gemm1 now overlaps sortA instead)
__global__ __launch_bounds__(256)
void sortB_k(const u32* __restrict__ tkey, const int* __restrict__ scnt,
             int* __restrict__ rowp, int* __restrict__ ssrc,
             int NA, int N, int nE) {
    __shared__ int h[256];
    __shared__ int offv[256];
    sortB_body(tkey, scnt, rowp, ssrc, NA, N, nE, blockIdx.x, h, offv);
}

// ---------------------------------------------------------------------------
// GEMM body (operand-swapped). LDS holds ONLY the X tile (34 KB). Weight
// A-fragments come straight from global (weights 256 KB total, L2-hot).
// nt-MAJOR dual-matrix schedule (round-6 spill post-mortem: arg2 of
// launch_bounds caps VGPR at 256/arg2 on this hipcc — 64 at arg2=4 — and
// the wi-sequential body needed ~130 live regs -> scratch storm). Both
// matrices of a store-pair run per output tile: per nt, 4 independent MFMA
// chains over kt, then one immediate dwordx4 store per mt. Live ~105 VGPR,
// bound (256,2) = proven-no-spill 128 cap.
// KS: per node 256 u16, k4/s4 interleaved. QV: q4/v4. Per wave, mt0+mt1
// stores cover a full 128B line per node (dense writes).
template<int F32>
__device__ __forceinline__
void gemm_body(int bid, u16* xs,
               const void* __restrict__ Xv, const u16* __restrict__ Wt,
               const float* __restrict__ bias,
               u16* __restrict__ KS, u16* __restrict__ QV, int nrows)
{
    const int tid  = threadIdx.x;
    const int wave = tid >> 6, lane = tid & 63;
    const int quad = lane >> 4, l16 = lane & 15;
    const int r0 = bid * 128;

    for (int p = 0; p < 8; ++p) {
        int c = p * 256 + tid;
        int row = c >> 4;
        int col = (c & 15) * 8;
        int gr = r0 + row; if (gr >= nrows) gr = nrows - 1;
        if (F32) {
            const float* sp = (const float*)Xv + (size_t)gr * 128 + col;
            float4 f0 = *(const float4*)(sp);
            float4 f1 = *(const float4*)(sp + 4);
            uint4 st;
            st.x = ((u32)f2bf(f0.y) << 16) | f2bf(f0.x);
            st.y = ((u32)f2bf(f0.w) << 16) | f2bf(f0.z);
            st.z = ((u32)f2bf(f1.y) << 16) | f2bf(f1.x);
            st.w = ((u32)f2bf(f1.w) << 16) | f2bf(f1.z);
            *(uint4*)(&xs[row * XS + col]) = st;
        } else {
            uint4 d = *(const uint4*)((const u16*)Xv + (size_t)gr * 128 + col);
            *(uint4*)(&xs[row * XS + col]) = d;
        }
    }
    __syncthreads();   // xs is read-only from here on: single barrier

    const int cbase = wave * 32;  // this wave's 32 output channels

    for (int pass = 0; pass < 2; ++pass) {
        const u16* WA = Wt + (size_t)(pass ? 0 : 1) * 16384;  // K : Q
        const u16* WB = Wt + (size_t)(pass ? 3 : 2) * 16384;  // S : V

        // both matrices' A-fragments straight from global (L2-hot): 64 VGPR
        bf16x8 afA0[4], afA1[4], afB0[4], afB1[4];
        for (int kt = 0; kt < 4; ++kt) {
            const int ro0 = (cbase + l16)      * 128 + kt * 32 + quad * 8;
            const int ro1 = (cbase + 16 + l16) * 128 + kt * 32 + quad * 8;
            afA0[kt] = *(const bf16x8*)(WA + ro0);
            afA1[kt] = *(const bf16x8*)(WA + ro1);
            afB0[kt] = *(const bf16x8*)(WB + ro0);
            afB1[kt] = *(const bf16x8*)(WB + ro1);
        }

        float4 bias4[2];
        if (pass) {
            bias4[0] = *(const float4*)(bias + cbase + quad * 4);
            bias4[1] = *(const float4*)(bias + cbase + 16 + quad * 4);
        }

        for (int nt = 0; nt < 8; ++nt) {
            f32x4 aA0 = (f32x4)0.0f, aA1 = (f32x4)0.0f;
            f32x4 aB0 = (f32x4)0.0f, aB1 = (f32x4)0.0f;
            for (int kt = 0; kt < 4; ++kt) {
                bf16x8 b = *(const bf16x8*)&xs[(nt * 16 + l16) * XS + kt * 32 + quad * 8];
                aA0 = __builtin_amdgcn_mfma_f32_16x16x32_bf16(afA0[kt], b, aA0, 0, 0, 0);
                aA1 = __builtin_amdgcn_mfma_f32_16x16x32_bf16(afA1[kt], b, aA1, 0, 0, 0);
                aB0 = __builtin_amdgcn_mfma_f32_16x16x32_bf16(afB0[kt], b, aB0, 0, 0, 0);
                aB1 = __builtin_amdgcn_mfma_f32_16x16x32_bf16(afB1[kt], b, aB1, 0, 0, 0);
            }
            int node = r0 + nt * 16 + l16;
            if (node >= nrows) continue;
            u16* rowbase = (pass ? KS : QV) + (size_t)node * 256;
            // mt = 0
            {
                float x0 = aA0[0] * NEG_LOG2E, x1 = aA0[1] * NEG_LOG2E;
                float x2 = aA0[2] * NEG_LOG2E, x3 = aA0[3] * NEG_LOG2E;
                float y0 = aB0[0], y1 = aB0[1], y2 = aB0[2], y3 = aB0[3];
                if (pass) { y0 += bias4[0].x; y1 += bias4[0].y; y2 += bias4[0].z; y3 += bias4[0].w; }
                uint4 out;
                out.x = ((u32)f2bf(x1) << 16) | f2bf(x0);
                out.y = ((u32)f2bf(x3) << 16) | f2bf(x2);
                out.z = ((u32)f2bf(y1) << 16) | f2bf(y0);
                out.w = ((u32)f2bf(y3) << 16) | f2bf(y2);
                *(uint4*)(rowbase + 2 * (cbase + quad * 4)) = out;
            }
            // mt = 1
            {
                float x0 = aA1[0] * NEG_LOG2E, x1 = aA1[1] * NEG_LOG2E;
                float x2 = aA1[2] * NEG_LOG2E, x3 = aA1[3] * NEG_LOG2E;
                float y0 = aB1[0], y1 = aB1[1], y2 = aB1[2], y3 = aB1[3];
                if (pass) { y0 += bias4[1].x; y1 += bias4[1].y; y2 += bias4[1].z; y3 += bias4[1].w; }
                uint4 out;
                out.x = ((u32)f2bf(x1) << 16) | f2bf(x0);
                out.y = ((u32)f2bf(x3) << 16) | f2bf(x2);
                out.z = ((u32)f2bf(y1) << 16) | f2bf(y0);
                out.w = ((u32)f2bf(y3) << 16) | f2bf(y2);
                *(uint4*)(rowbase + 2 * (cbase + 16 + quad * 4)) = out;
            }
        }
    }
}

// Launch 4: layer-1 GEMM (first gb blocks — the head's long pole, starts
// first) + sortA coarse scatter (remaining NA blocks). sortA needs scnt
// (scan), gemm1 needs only Wt (prep) — independent, so they overlap here
// (round 7 overlapped gemm1 with the SHORT sortB and ran sortA serial).
__global__ __launch_bounds__(256, 2)
void sortA_gemm1(const int* __restrict__ src, const int* __restrict__ dst,
                 const int* __restrict__ scnt, u32* __restrict__ tkey,
                 int nE, int NA, int nbuck, int gb,
                 const float* __restrict__ x0, const u16* __restrict__ Wt,
                 const float* __restrict__ bias,
                 u16* __restrict__ KS, u16* __restrict__ QV, int N)
{
    __shared__ u16 xs[128 * XS];
    if ((int)blockIdx.x < gb) {
        gemm_body<1>(blockIdx.x, xs, x0, Wt, bias, KS, QV, N);
    } else {
        int* lh    = (int*)xs;
        int* lbase = lh + 512;
        int t = threadIdx.x, b = blockIdx.x - gb;
        for (int i = t; i < nbuck; i += 256) { lh[i] = 0; lbase[i] = scnt[i * NA + b]; }
        __syncthreads();
        int i0 = b * CSR_CH, iend = min(i0 + CSR_CH, nE);
        for (int i = i0 + t; i < iend; i += 256) {
            int d = dst[i], s = src[i];
            int bk = d >> 8;
            int r = atomicAdd(&lh[bk], 1);
            tkey[lbase[bk] + r] = ((u32)(d & 255) << 24) | (u32)s;
        }
    }
}

// Layer-2 standalone GEMM
__global__ __launch_bounds__(256, 2)
void gemm_l2(const u16* __restrict__ X, const u16* __restrict__ Wt,
             const float* __restrict__ bias,
             u16* __restrict__ KS, u16* __restrict__ QV, int nrows)
{
    __shared__ u16 xs[128 * XS];
    gemm_body<0>(blockIdx.x, xs, X, Wt, bias, KS, QV, nrows);
}

// ---------------------------------------------------------------------------
// CSR gather-reduce edge phase: one wave per dst node, TWO edges per load
// (half-wave per edge, lane covers 4 channels via one dwordx4 row load).
// Row-level software pipeline: next row's ssrc block, merged KS row, and row
// pointers are in flight during current row's compute; next row's first
// gather group issued over the epilogue. KS is k4/s4-interleaved so one
// dwordx4 fetches K+S for a 4-channel group.
template<int MODE>
__global__ __launch_bounds__(256)
void edge_csr2(const int* __restrict__ rowp, const int* __restrict__ ssrc,
               const u16* __restrict__ KS, const u16* __restrict__ QV,
               u16* __restrict__ Xout,
               const float* __restrict__ Wk3, const float* __restrict__ Wq3,
               const float* __restrict__ Wv3, const float* __restrict__ Ws3,
               const float* __restrict__ b3,
               float* __restrict__ k3, float2* __restrict__ qv3,
               float* __restrict__ s3, int N)
{
    const int lane = threadIdx.x & 63;
    const int half = lane >> 5;
    const int t    = lane & 31;       // channel group: channels 4t..4t+3
    int gw = blockIdx.x * (blockDim.x >> 6) + (threadIdx.x >> 6);
    int nw = gridDim.x * (blockDim.x >> 6);

    float4 wk4, wq4, wv4, ws4;
    float bias3 = 0.0f;
    if (MODE == 1) {
        wk4 = *(const float4*)(Wk3 + 4 * t);
        wq4 = *(const float4*)(Wq3 + 4 * t);
        wv4 = *(const float4*)(Wv3 + 4 * t);
        ws4 = *(const float4*)(Ws3 + 4 * t);
        bias3 = b3[0];
    }

#define LOAD2(S0, S1) (*((const uint4*)(QV + (size_t)(half ? (S1) : (S0)) * 256) + t))
#define COMP(QVv, A0, A1, A2, A3)                                             \
    {                                                                         \
        float q0_, q1_, q2_, q3_, v0_, v1_, v2_, v3_;                         \
        bfu2((QVv).x, q0_, q1_); bfu2((QVv).y, q2_, q3_);                     \
        bfu2((QVv).z, v0_, v1_); bfu2((QVv).w, v2_, v3_);                     \
        A0 += gate(k0 + q0_) * v0_;  A1 += gate(k1 + q1_) * v1_;              \
        A2 += gate(k2 + q2_) * v2_;  A3 += gate(k3v + q3_) * v3_;             \
    }
// load one 4-edge group g: two dwordx4 gathers (edges 4g..4g+3)
#define LOADG(SVV, G, RA, RB)                                                 \
    {                                                                         \
        int s0_ = __builtin_amdgcn_readlane(SVV, 4 * (G));                    \
        int s1_ = __builtin_amdgcn_readlane(SVV, 4 * (G) + 1);                \
        int s2_ = __builtin_amdgcn_readlane(SVV, 4 * (G) + 2);                \
        int s3_ = __builtin_amdgcn_readlane(SVV, 4 * (G) + 3);                \
        RA = LOAD2(s0_, s1_); RB = LOAD2(s2_, s3_);                           \
    }

    int d = gw;
    int beg = 0, end = 0, sv = 0;
    uint4 ks; ks.x = ks.y = ks.z = ks.w = 0u;
    if (d < N) {
        beg = rowp[d]; end = rowp[d + 1];
        int e  = beg + lane;
        int ec = (end > beg) ? ((e < end) ? e : end - 1) : 0;
        sv = ssrc[ec];
        ks = *((const uint4*)KS + (size_t)d * 32 + t);
    }
    int havePF = 0;
    uint4 pA, pB;
    pA.x = pA.y = pA.z = pA.w = 0u;
    pB = pA;

    while (d < N) {
        int dn = d + nw;
        int begN = 0, endN = 0, svN = 0;
        uint4 ksN; ksN.x = ksN.y = ksN.z = ksN.w = 0u;
        if (dn < N) {
            begN = rowp[dn]; endN = rowp[dn + 1];
            int e  = begN + lane;
            int ec = (endN > begN) ? ((e < endN) ? e : endN - 1) : 0;
            svN = ssrc[ec];
            ksN = *((const uint4*)KS + (size_t)dn * 32 + t);
        }

        float k0, k1, k2, k3v;
        bfu2(ks.x, k0, k1); bfu2(ks.y, k2, k3v);
        float a0 = 0.f, a1 = 0.f, a2 = 0.f, a3 = 0.f;
        float e0 = 0.f, e1 = 0.f, e2 = 0.f, e3 = 0.f;

        for (int base = beg; base < end; base += 64) {
            if (base > beg) {            // rare multi-block row: reload sv
                int e  = base + lane;
                int ec = (e < end) ? e : end - 1;
                sv = ssrc[ec];
            }
            int m = end - base; if (m > 64) m = 64;
            int ng = m >> 2;
            int j = ng << 2;
            if (ng > 0) {
                uint4 xA, xB, yA, yB;
                if (havePF && base == beg) { xA = pA; xB = pB; }
                else LOADG(sv, 0, xA, xB);
                int g = 1;
                for (; g + 1 < ng; g += 2) {          // ping-pong groups
                    LOADG(sv, g, yA, yB);
                    COMP(xA, a0, a1, a2, a3);
                    COMP(xB, e0, e1, e2, e3);
                    LOADG(sv, g + 1, xA, xB);
                    COMP(yA, a0, a1, a2, a3);
                    COMP(yB, e0, e1, e2, e3);
                }
                if (g < ng) {
                    LOADG(sv, g, yA, yB);
                    COMP(xA, a0, a1, a2, a3);
                    COMP(xB, e0, e1, e2, e3);
                    COMP(yA, a0, a1, a2, a3);
                    COMP(yB, e0, e1, e2, e3);
                } else {
                    COMP(xA, a0, a1, a2, a3);
                    COMP(xB, e0, e1, e2, e3);
                }
            }
            if (j + 2 <= m) {
                int s0 = __builtin_amdgcn_readlane(sv, j);
                int s1 = __builtin_amdgcn_readlane(sv, j + 1);
                uint4 qA = LOAD2(s0, s1);
                COMP(qA, a0, a1, a2, a3);
                j += 2;
            }
            if (j < m) {  // single odd edge: only half 0 accumulates
                int s0i = __builtin_amdgcn_readlane(sv, j);
                uint4 qv_ = *((const uint4*)(QV + (size_t)s0i * 256) + t);
                float q0_, q1_, q2_, q3_, v0_, v1_, v2_, v3_;
                bfu2(qv_.x, q0_, q1_); bfu2(qv_.y, q2_, q3_);
                bfu2(qv_.z, v0_, v1_); bfu2(qv_.w, v2_, v3_);
                if (half == 0) {
                    a0 += gate(k0 + q0_) * v0_;  a1 += gate(k1 + q1_) * v1_;
                    a2 += gate(k2 + q2_) * v2_;  a3 += gate(k3v + q3_) * v3_;
                }
            }
        }

        // early-issue next row's first gather group (svN has arrived by now);
        // it flies over the epilogue + next-row prologue.
        havePF = 0;
        if (dn < N) {
            int mN = endN - begN; if (mN > 64) mN = 64;
            if ((mN >> 2) > 0) {
                int s0_ = __builtin_amdgcn_readlane(svN, 0);
                int s1_ = __builtin_amdgcn_readlane(svN, 1);
                int s2_ = __builtin_amdgcn_readlane(svN, 2);
                int s3_ = __builtin_amdgcn_readlane(svN, 3);
                pA = LOAD2(s0_, s1_);
                pB = LOAD2(s2_, s3_);
                havePF = 1;
            }
        }
#undef LOADG
#undef LOAD2
#undef COMP

        a0 += e0; a1 += e1; a2 += e2; a3 += e3;
        a0 += __shfl_xor(a0, 32);
        a1 += __shfl_xor(a1, 32);
        a2 += __shfl_xor(a2, 32);
        a3 += __shfl_xor(a3, 32);

        float s0f, s1f, s2f, s3f;
        bfu2(ks.z, s0f, s1f); bfu2(ks.w, s2f, s3f);
        float r0 = fmaxf(s0f + a0, 0.f);
        float r1 = fmaxf(s1f + a1, 0.f);
        float r2 = fmaxf(s2f + a2, 0.f);
        float r3 = fmaxf(s3f + a3, 0.f);

        if (MODE == 0) {
            if (half == 0) {
                uint2 st;
                st.x = ((u32)f2bf(r1) << 16) | f2bf(r0);
                st.y = ((u32)f2bf(r3) << 16) | f2bf(r2);
                *(uint2*)(Xout + (size_t)d * 128 + t * 4) = st;
            }
        } else {
            float pk = r0 * wk4.x + r1 * wk4.y + r2 * wk4.z + r3 * wk4.w;
            float pq = r0 * wq4.x + r1 * wq4.y + r2 * wq4.z + r3 * wq4.w;
            float pv = r0 * wv4.x + r1 * wv4.y + r2 * wv4.z + r3 * wv4.w;
            float ps = r0 * ws4.x + r1 * ws4.y + r2 * ws4.z + r3 * ws4.w;
            for (int off = 1; off < 32; off <<= 1) {
                pk += __shfl_xor(pk, off);
                pq += __shfl_xor(pq, off);
                pv += __shfl_xor(pv, off);
                ps += __shfl_xor(ps, off);
            }
            if (lane == 0) {
                k3[d]  = NEG_LOG2E * pk;
                qv3[d] = make_float2(NEG_LOG2E * pq, pv);
                s3[d]  = ps + bias3;
            }
        }

        d = dn; beg = begN; end = endN; sv = svN; ks = ksN;
    }
}

// ---------------------------------------------------------------------------
// CSR edge phase, Dout=1: wave per node; qv3 packed float2 (one 8B gather).
// Same 1-deep row prefetch (rowp/ssrc/k3/s3 for the next row in flight).
__global__ __launch_bounds__(256)
void edge3_csr(const int* __restrict__ rowp, const int* __restrict__ ssrc,
               const float* __restrict__ k3, const float2* __restrict__ qv3,
               const float* __restrict__ s3, float* __restrict__ outp, int N)
{
    int lane = threadIdx.x & 63;
    int gw = blockIdx.x * (blockDim.x >> 6) + (threadIdx.x >> 6);
    int nw = gridDim.x * (blockDim.x >> 6);

    int d = gw;
    int beg = 0, end = 0, sv = 0;
    float kd = 0.f, sd = 0.f;
    if (d < N) {
        beg = rowp[d]; end = rowp[d + 1];
        int e  = beg + lane;
        int ec = (end > beg) ? ((e < end) ? e : end - 1) : 0;
        sv = ssrc[ec];
        kd = k3[d]; sd = s3[d];
    }
    while (d < N) {
        int dn = d + nw;
        int begN = 0, endN = 0, svN = 0;
        float kdN = 0.f, sdN = 0.f;
        if (dn < N) {
            begN = rowp[dn]; endN = rowp[dn + 1];
            int e  = begN + lane;
            int ec = (endN > begN) ? ((e < endN) ? e : endN - 1) : 0;
            svN = ssrc[ec];
            kdN = k3[dn]; sdN = s3[dn];
        }

        float sum = 0.0f;
        int m = end - beg;
        if (lane < m) {                    // first 64 edges via prefetched sv
            float2 qv = qv3[sv];
            sum = gate(kd + qv.x) * qv.y;
        }
        for (int e = beg + 64 + lane; e < end; e += 64) {   // rare deg>64
            float2 qv = qv3[ssrc[e]];
            sum += gate(kd + qv.x) * qv.y;
        }
        for (int off = 32; off > 0; off >>= 1) sum += __shfl_xor(sum, off);
        if (lane == 0) outp[d] = sd + sum;

        d = dn; beg = begN; end = endN; sv = svN; kd = kdN; sd = sdN;
    }
}

// ---------------------------------------------------------------------------
extern "C" void kernel_launch(void* const* d_in, const int* in_sizes, int n_in,
                              void* d_out, int out_size, void* d_ws, size_t ws_size,
                              hipStream_t stream)
{
    const float* x0 = (const float*)d_in[0];
    const int*   ei = (const int*)d_in[1];
    const int    N  = in_sizes[0] / 128;   // 100000
    const int    E  = in_sizes[1] / 2;     // 1600000
    const int* src = ei;
    const int* dst = ei + E;

    const int NBUCK = (N + 255) >> 8;              // 391
    const int NA    = (E + CSR_CH - 1) / CSR_CH;   // 782
    const int M     = NBUCK * NA;                  // 305,762
    const int nparts = (M + 1023) / 1024;          // 299

    char* ws = (char*)d_ws;
    size_t off = 0;
    auto carve = [&](size_t bytes) { void* p = ws + off; off += (bytes + 255) & ~(size_t)255; return p; };
    u16*    Wt   = (u16*)carve((size_t)8 * 16384 * sizeof(u16));
    u16*    bufX = (u16*)carve((size_t)N * 128 * sizeof(u16));
    u16*    KS   = (u16*)carve((size_t)N * 256 * sizeof(u16));
    u16*    QV   = (u16*)carve((size_t)N * 256 * sizeof(u16));
    int*    ssrc = (int*)carve((size_t)E * sizeof(int));
    u32*    tkey = (u32*)carve((size_t)E * sizeof(u32));
    int*    rowp = (int*)carve((size_t)(N + 1) * sizeof(int));
    int*    cnt  = (int*)carve((size_t)M * sizeof(int));
    int*    scnt = (int*)carve((size_t)(M + 1) * sizeof(int));
    int*    part = (int*)carve((size_t)512 * sizeof(int));
    float*  k3   = (float*)carve((size_t)N * sizeof(float));
    float2* qv3  = (float2*)carve((size_t)N * sizeof(float2));
    float*  s3   = (float*)carve((size_t)N * sizeof(float));

    P8 wp;
    wp.p[0] = (const float*)d_in[2];  wp.p[1] = (const float*)d_in[3];
    wp.p[2] = (const float*)d_in[4];  wp.p[3] = (const float*)d_in[5];
    wp.p[4] = (const float*)d_in[7];  wp.p[5] = (const float*)d_in[8];
    wp.p[6] = (const float*)d_in[9];  wp.p[7] = (const float*)d_in[10];

    int gb = (N + 127) / 128;   // 782

    // 1: weight prep + coarse histogram (independent, one launch)
    prep_hist_k<<<64 + NA, 256, 0, stream>>>(wp, Wt, dst, cnt, E, NA, NBUCK);
    // 2-3: scan
    scan_part_k<<<nparts, 256, 0, stream>>>(cnt, part, M);
    scan_emit2_k<<<nparts, 256, 0, stream>>>(cnt, part, scnt, M, E, nparts);
    // 4: layer-1 GEMM (long pole, blocks first) + sortA coarse scatter
    sortA_gemm1<<<gb + NA, 256, 0, stream>>>(src, dst, scnt, tkey, E, NA, NBUCK, gb,
        x0, Wt, (const float*)d_in[6], KS, QV, N);
    // 5: fine grouping (standalone, short)
    sortB_k<<<NBUCK, 256, 0, stream>>>(tkey, scnt, rowp, ssrc, NA, N, E);
    // 6: layer-1 edge
    edge_csr2<0><<<4096, 256, 0, stream>>>(rowp, ssrc, KS, QV, bufX,
        nullptr, nullptr, nullptr, nullptr, nullptr, nullptr, nullptr, nullptr, N);
    // 7: layer-2 GEMM
    gemm_l2<<<gb, 256, 0, stream>>>(bufX, Wt + 4 * 16384, (const float*)d_in[11], KS, QV, N);
    // 8: layer-2 edge (+ fused layer-3 GEMV)
    edge_csr2<1><<<4096, 256, 0, stream>>>(rowp, ssrc, KS, QV, nullptr,
        (const float*)d_in[12], (const float*)d_in[13], (const float*)d_in[14],
        (const float*)d_in[15], (const float*)d_in[16],
        k3, qv3, s3, N);
    // 9: layer-3 edge -> d_out
    edge3_csr<<<2048, 256, 0, stream>>>(rowp, ssrc, k3, qv3, s3, (float*)d_out, N);
}